// Round 3
// baseline (1797.717 us; speedup 1.0000x reference)
//
#include <hip/hip_runtime.h>

// Dims fixed by the reference
#define LAY 2
#define BATCH 64
#define TMAX 512
#define DIM 256
#define AST 264    // LDS activation row stride (bytes, fp8)
#define CHUNK 16   // pipeline handoff granularity (timesteps)

typedef float floatx4 __attribute__((ext_vector_type(4)));
typedef __bf16 bf16x8 __attribute__((ext_vector_type(8)));
#define MFMA_FP8  __builtin_amdgcn_mfma_f32_16x16x32_fp8_fp8
#define MFMA_BF16 __builtin_amdgcn_mfma_f32_16x16x32_bf16

// d_ws layout (requires ws >= ~74 MB)
#define OFF_WPW 0x60000     // bf16 B-frag W-mats, 6 x 128 KB  (ends 0x120000)
#define OFF_FLG 0x150000    // flags: [0..15] projA, [16..19] scan0, [20..35] projB
#define OFF_XP  0x200000    // layer-0 X-projections fp8, 25.2 MB
#define OFF_HP  0x1C00000   // layer-1 input projections fp8, 25.2 MB
#define OFF_HN  0x3600000   // hn0 bf16 [b*512+t][256], 16.8 MB

__device__ __forceinline__ unsigned short f2bf(float f) {
    unsigned int u = __float_as_uint(f);
    unsigned int r = u + 0x7fffu + ((u >> 16) & 1u);  // RNE
    return (unsigned short)(r >> 16);
}
__device__ __forceinline__ unsigned int pk2(float a, float b) {
    return (unsigned int)__builtin_amdgcn_cvt_pk_fp8_f32(a, b, 0, false);  // OCP e4m3 x2
}
__device__ __forceinline__ unsigned char f2q(float a) { return (unsigned char)(pk2(a, a) & 0xff); }
__device__ __forceinline__ void unp4(unsigned int u, float* f) {
    auto lo = __builtin_amdgcn_cvt_pk_f32_fp8((int)u, false);
    auto hi = __builtin_amdgcn_cvt_pk_f32_fp8((int)u, true);
    f[0] = lo[0]; f[1] = lo[1]; f[2] = hi[0]; f[3] = hi[1];
}
__device__ __forceinline__ float sigf(float x) { return 1.f / (1.f + __expf(-x)); }
// tanh(y) = 2*sigmoid(2y) - 1
__device__ __forceinline__ float tanhfast2y(float twoy) { return 2.f * sigf(twoy) - 1.f; }

// ---------------------------------------------------------------------------
// Weight prep (identical math). Zeroes 64 pipeline flags and d_out.
// ---------------------------------------------------------------------------
__global__ void prep_weights(const float* __restrict__ Wz, const float* __restrict__ Wr,
                             const float* __restrict__ Wh, const float* __restrict__ Uz,
                             const float* __restrict__ Ur, const float* __restrict__ Uh,
                             unsigned char* __restrict__ ws, float* __restrict__ out) {
    int T = blockIdx.x * 256 + threadIdx.x;  // 1536*256 = 393216
    if (T == 0) out[0] = 0.f;
    if (T < 64) ((int*)(ws + OFF_FLG))[T] = 0;   // pipeline flags (ws re-poisoned each call)
    if (T < 196608) {  // U-mats, fp8
        int e = T & 3, half = (T >> 2) & 1, lane = (T >> 3) & 63;
        int kp = (T >> 9) & 3, nt = (T >> 11) & 15, mu = T >> 15;
        int g = mu % 3, l = mu / 3;
        const float* s = (g == 0 ? Uz : g == 1 ? Ur : Uh) + l * 65536;
        int n  = nt * 16 + (lane & 15);
        int k0 = (2 * kp + half) * 32 + (lane >> 4) * 8 + 2 * e;
        float w0 = s[(k0 << 8) + n] * 8.f;        // x8: dodge e4m3 denormals
        float w1 = s[((k0 + 1) << 8) + n] * 8.f;  // undone by 0.125 post-acc
        int addr = ((mu * 16 + nt) * 4 + kp) * 1024 + lane * 16 + half * 8 + 2 * e;
        *(unsigned short*)(ws + addr) = (unsigned short)(pk2(w0, w1) & 0xffff);
    } else {           // W-mats, bf16
        int T2 = T - 196608;
        int e = T2 & 3, lane = (T2 >> 2) & 63;
        int kf = (T2 >> 8) & 7, nt = (T2 >> 11) & 15, mw = T2 >> 15;
        int g = mw % 3, l = mw / 3;
        const float* s = (g == 0 ? Wz : g == 1 ? Wr : Wh) + l * 65536;
        int n  = nt * 16 + (lane & 15);
        int k0 = kf * 32 + (lane >> 4) * 8 + 2 * e;
        unsigned int v = (unsigned int)f2bf(s[(k0 << 8) + n]) |
                         ((unsigned int)f2bf(s[((k0 + 1) << 8) + n]) << 16);
        int addr = ((mw * 16 + nt) * 8 + kf) * 1024 + lane * 16 + 4 * e;
        *(unsigned int*)(ws + OFF_WPW + addr) = v;
    }
}

// ---------------------------------------------------------------------------
// Projection GEMM body, chunk-synchronized; this WG owns 4 t per chunk.
// DOWAIT: wait on single upstream flag. Always posts its own flag per chunk.
// ---------------------------------------------------------------------------
template <int F32SRC, int DOWAIT>
__device__ __forceinline__ void proj_body(const void* __restrict__ src,
                                          const unsigned char* __restrict__ wpW,
                                          unsigned int* __restrict__ xpo, int matbase,
                                          int bg, int p, int tmax, int* wf, int* pf) {
    const int tid = threadIdx.x, wave = tid >> 6, lane = tid & 63;
    const int l15 = lane & 15, quad = lane >> 4;
    const unsigned char* bz = wpW + (size_t)(((matbase + 0) * 16 + wave) * 8) * 1024 + lane * 16;
    const unsigned char* br = wpW + (size_t)(((matbase + 1) * 16 + wave) * 8) * 1024 + lane * 16;
    const unsigned char* bh = wpW + (size_t)(((matbase + 2) * 16 + wave) * 8) * 1024 + lane * 16;

    for (int base = 0; base < tmax; base += CHUNK) {
        if (DOWAIT) {
            const int target = (base + CHUNK < tmax) ? base + CHUNK : tmax;
            if (tid == 0) {
                int vv, g = 0;
                for (;;) {
                    vv = __hip_atomic_load(wf, __ATOMIC_RELAXED, __HIP_MEMORY_SCOPE_AGENT);
                    if (vv >= target || ++g > (1 << 19)) break;  // fail visibly, never hang
                    __builtin_amdgcn_s_sleep(2);
                }
                __threadfence();   // acquire: see upstream chunk data
            }
            __syncthreads();       // no wave reads src before the inv
        }

        const int t0 = base + p * 4;
        const int t1 = (t0 + 4 < tmax) ? t0 + 4 : tmax;
        for (int t = t0; t < t1; ++t) {
            const size_t rowoff = ((size_t)(bg * 16 + l15) * 512 + t) * 256;
            bf16x8 af[8];
            if (F32SRC) {
                const float* s = (const float*)src + rowoff;
#pragma unroll
                for (int kf = 0; kf < 8; ++kf) {
                    float4 a = *(const float4*)(s + kf * 32 + quad * 8);
                    float4 b = *(const float4*)(s + kf * 32 + quad * 8 + 4);
                    union { unsigned short u[8]; bf16x8 v; } cv;
                    cv.u[0] = f2bf(a.x); cv.u[1] = f2bf(a.y); cv.u[2] = f2bf(a.z); cv.u[3] = f2bf(a.w);
                    cv.u[4] = f2bf(b.x); cv.u[5] = f2bf(b.y); cv.u[6] = f2bf(b.z); cv.u[7] = f2bf(b.w);
                    af[kf] = cv.v;
                }
            } else {
                const unsigned short* s = (const unsigned short*)src + rowoff;
#pragma unroll
                for (int kf = 0; kf < 8; ++kf) af[kf] = *(const bf16x8*)(s + kf * 32 + quad * 8);
            }
            floatx4 az = {0.f, 0.f, 0.f, 0.f}, ar = az, ah = az;
#pragma unroll
            for (int kf = 0; kf < 8; ++kf) {
                az = MFMA_BF16(af[kf], *(const bf16x8*)(bz + kf * 1024), az, 0, 0, 0);
                ar = MFMA_BF16(af[kf], *(const bf16x8*)(br + kf * 1024), ar, 0, 0, 0);
                ah = MFMA_BF16(af[kf], *(const bf16x8*)(bh + kf * 1024), ah, 0, 0, 0);
            }
            const size_t ob = (size_t)(bg * 512 + t) * 3072 + wave * 64 + lane;
            xpo[ob]        = pk2(16.f * az[0], 16.f * az[1]) | (pk2(16.f * az[2], 16.f * az[3]) << 16);
            xpo[ob + 1024] = pk2(16.f * ar[0], 16.f * ar[1]) | (pk2(16.f * ar[2], 16.f * ar[3]) << 16);
            xpo[ob + 2048] = pk2(16.f * ah[0], 16.f * ah[1]) | (pk2(16.f * ah[2], 16.f * ah[3]) << 16);
        }

        __syncthreads();   // all waves' stores drained (vmcnt0 before barrier)
        if (tid == 0) {
            __threadfence();   // release: push chunk to coherent point
            __hip_atomic_store(pf, base + CHUNK, __ATOMIC_RELEASE, __HIP_MEMORY_SCOPE_AGENT);
        }
    }
}

// ---------------------------------------------------------------------------
// GRU scan body. WAIT==1: wait on MIN of 4 upstream flags. POST==1: publish
// pflag per CHUNK. Input projections register-prefetched one step ahead
// (clamped to the ready horizon) to keep HBM/IF$ latency off the critical
// path. MFMA accumulation chains split 2x to halve dep-latency.
// ---------------------------------------------------------------------------
template <int SCORE, int WAIT, int POST>
__device__ __forceinline__ void scan_body(
    const unsigned int* __restrict__ xp, const unsigned char* __restrict__ wpU,
    int lbase, int bg, unsigned short* __restrict__ hnout,
    const int* __restrict__ xlen, const float* __restrict__ xlab,
    const float* __restrict__ Wo, float* __restrict__ out,
    int* wflags, int* pflag,
    unsigned char (*s1q)[AST], unsigned char (*rsq)[AST], float (*s1o)[264],
    float* wo1s, int* s_rdy, int tmax)
{
    const int tid = threadIdx.x, wave = tid >> 6, lane = tid & 63;
    const int l15 = lane & 15, quad = lane >> 4;
    const int b0 = bg * 16;

    for (int i = tid; i < 16 * AST; i += 1024) ((unsigned char*)s1q)[i] = 0;
    if (SCORE && tid < DIM) wo1s[tid] = Wo[2 * tid + 1];
    const int lenr = xlen[b0 + l15];
    const float labr = SCORE ? xlab[b0 + l15] : 0.f;
    (void)lenr; (void)labr;

    const int nt = wave;
    const int colA = nt * 16 + l15, rowb = quad * 4;

    // register-resident U fragments for this wave's 16-col tile
    long uz[8], ur[8], uh[8];
    {
        const unsigned char* pz = wpU + (size_t)(((lbase + 0) * 16 + nt) * 4) * 1024 + lane * 16;
        const unsigned char* pr = wpU + (size_t)(((lbase + 1) * 16 + nt) * 4) * 1024 + lane * 16;
        const unsigned char* ph = wpU + (size_t)(((lbase + 2) * 16 + nt) * 4) * 1024 + lane * 16;
#pragma unroll
        for (int kf = 0; kf < 8; ++kf) {
            int o = (kf >> 1) * 1024 + (kf & 1) * 8;
            uz[kf] = *(const long*)(pz + o);
            ur[kf] = *(const long*)(pr + o);
            uh[kf] = *(const long*)(ph + o);
        }
    }
    float s1r[4] = {};
    float accl = 0.f;
    int ready = 0;
    unsigned int cz = 0, cr = 0, ch = 0;
    bool have = false;
    __syncthreads();

    for (int t = 0; t < tmax; ++t) {
        if (WAIT && t >= ready) {
            if (tid == 0) {
                int vv, g = 0;
                for (;;) {
                    int m0 = __hip_atomic_load(wflags + 0, __ATOMIC_RELAXED, __HIP_MEMORY_SCOPE_AGENT);
                    int m1 = __hip_atomic_load(wflags + 1, __ATOMIC_RELAXED, __HIP_MEMORY_SCOPE_AGENT);
                    int m2 = __hip_atomic_load(wflags + 2, __ATOMIC_RELAXED, __HIP_MEMORY_SCOPE_AGENT);
                    int m3 = __hip_atomic_load(wflags + 3, __ATOMIC_RELAXED, __HIP_MEMORY_SCOPE_AGENT);
                    int a = m0 < m1 ? m0 : m1, b = m2 < m3 ? m2 : m3;
                    vv = a < b ? a : b;
                    if (vv > t || ++g > (1 << 19)) break;   // fail visibly, never hang
                    __builtin_amdgcn_s_sleep(2);
                }
                __threadfence();          // agent acquire before data reads
                *s_rdy = vv > t ? vv : t + 1;
            }
            __syncthreads();
            ready = *s_rdy;
        }

        if (!have) {   // chunk boundary (or t=0): synchronous load of this step
            const unsigned int* xpt = xp + (size_t)(bg * 512 + t) * 3072 + lane;
            cz = xpt[nt * 64];
            cr = xpt[1024 + nt * 64];
            ch = xpt[2048 + nt * 64];
        }
        // prefetch next step if already published (hides HBM/IF$ latency)
        const int lim = WAIT ? (ready < tmax ? ready : tmax) : tmax;
        const bool pfn = (t + 1 < lim);
        unsigned int nz = 0, nr = 0, nh = 0;
        if (pfn) {
            const unsigned int* xpn = xp + (size_t)(bg * 512 + t + 1) * 3072 + lane;
            nz = xpn[nt * 64];
            nr = xpn[1024 + nt * 64];
            nh = xpn[2048 + nt * 64];
        }

        // ---- phase 1: r (critical path) + z-MFMAs (accs dangle, split 2x) ----
        long sf[8];
#pragma unroll
        for (int kf = 0; kf < 8; ++kf) sf[kf] = *(const long*)&s1q[l15][kf * 32 + quad * 8];
        floatx4 zer = {0.f, 0.f, 0.f, 0.f};
        floatx4 ra0 = zer, ra1 = zer, za0 = zer, za1 = zer;
#pragma unroll
        for (int kf = 0; kf < 4; ++kf) {
            ra0 = MFMA_FP8(sf[kf],     ur[kf],     ra0, 0, 0, 0);
            za0 = MFMA_FP8(sf[kf],     uz[kf],     za0, 0, 0, 0);
            ra1 = MFMA_FP8(sf[kf + 4], ur[kf + 4], ra1, 0, 0, 0);
            za1 = MFMA_FP8(sf[kf + 4], uz[kf + 4], za1, 0, 0, 0);
        }
        floatx4 ra = ra0 + ra1;
        float xrf[4];
        unp4(cr, xrf);
#pragma unroll
        for (int i = 0; i < 4; ++i) {
            float r = sigf(0.125f * ra[i] + 0.0625f * xrf[i]);
            rsq[rowb + i][colA] = f2q(r * s1r[i]);
        }
        __syncthreads();

        // ---- phase 2: h (split 2x); z-sigmoid overlaps the Uh MFMA ----
        long rf[8];
#pragma unroll
        for (int kf = 0; kf < 8; ++kf) rf[kf] = *(const long*)&rsq[l15][kf * 32 + quad * 8];
        floatx4 ha0 = zer, ha1 = zer;
#pragma unroll
        for (int kf = 0; kf < 4; ++kf) {
            ha0 = MFMA_FP8(rf[kf],     uh[kf],     ha0, 0, 0, 0);
            ha1 = MFMA_FP8(rf[kf + 4], uh[kf + 4], ha1, 0, 0, 0);
        }
        floatx4 ha = ha0 + ha1;
        floatx4 za = za0 + za1;
        float xzf[4], xhf[4];
        unp4(cz, xzf); unp4(ch, xhf);
#pragma unroll
        for (int i = 0; i < 4; ++i) {
            float z = sigf(0.125f * za[i] + 0.0625f * xzf[i]);
            float h = tanhfast2y(0.25f * ha[i] + 0.125f * xhf[i]);
            float hn = (1.f - z) * s1r[i] + z * h;
            s1r[i] = hn;
            s1q[rowb + i][colA] = f2q(hn);
            s1o[rowb + i][colA] = hn;
        }
        __syncthreads();

        if (!SCORE) {
            const int r = tid >> 6, c = (tid & 63) * 4;
            float4 f0 = *(const float4*)&s1o[r][c];
            uint2 o2;
            o2.x = f2bf(f0.x) | ((unsigned)f2bf(f0.y) << 16);
            o2.y = f2bf(f0.z) | ((unsigned)f2bf(f0.w) << 16);
            *(uint2*)(hnout + ((size_t)(b0 + r) * 512 + t) * 256 + c) = o2;
        } else if (wave == 0) {
            const int row = l15, c0 = quad * 64;
            float p = 0.f;
#pragma unroll
            for (int u = 0; u < 64; u += 4) {
                float4 sv = *(const float4*)&s1o[row][c0 + u];
                float4 wv = *(const float4*)&wo1s[c0 + u];
                p = fmaf(sv.x, wv.x, p); p = fmaf(sv.y, wv.y, p);
                p = fmaf(sv.z, wv.z, p); p = fmaf(sv.w, wv.w, p);
            }
            p += __shfl_xor(p, 16);
            p += __shfl_xor(p, 32);
            if (lane < 16 && t < lenr) {
                float sc = sigf(p);
                float d = labr - sc;
                accl = fmaf(d, d, accl);
            }
        }

        if (POST && (((t & (CHUNK - 1)) == (CHUNK - 1)) || t == tmax - 1)) {
            __syncthreads();   // all waves' HN stores drained (vmcnt0 before barrier)
            if (tid == 0) {
                __threadfence();   // agent release: push chunk data to coherent point
                __hip_atomic_store(pflag, t + 1, __ATOMIC_RELEASE, __HIP_MEMORY_SCOPE_AGENT);
            }
        }

        cz = nz; cr = nr; ch = nh; have = pfn;
    }

    if (SCORE && wave == 0) {
        accl += __shfl_xor(accl, 1);
        accl += __shfl_xor(accl, 2);
        accl += __shfl_xor(accl, 4);
        accl += __shfl_xor(accl, 8);
        if (lane == 0) atomicAdd(out, accl);
    }
}

// ---------------------------------------------------------------------------
// Fused 4-stage pipeline, 40 WGs (all trivially co-resident):
//   blocks  0-15: projA  XP[t] = x[t] @ W(l0);  4 WGs/bg, posts flags[bg*4+p]
//   blocks 16-19: scan0  (waits min of bg's 4 projA flags, posts flags[16+bg])
//   blocks 20-35: projB  HP[t] = HN[t] @ W(l1); waits flags[16+bg],
//                 posts flags[20+bg*4+p]
//   blocks 36-39: scan1 + loss (waits min of bg's 4 projB flags)
// ---------------------------------------------------------------------------
__global__ __launch_bounds__(1024, 4) void fused_pipeline(
    const float* __restrict__ x,
    unsigned int* __restrict__ XP, unsigned int* __restrict__ HP,
    const unsigned char* __restrict__ wpU, const unsigned char* __restrict__ wpW,
    unsigned short* __restrict__ HN,
    const int* __restrict__ xlen, const float* __restrict__ xlab,
    const float* __restrict__ Wo, float* __restrict__ out, int* flags)
{
    __shared__ __align__(16) unsigned char s1q[16][AST];
    __shared__ __align__(16) unsigned char rsq[16][AST];
    __shared__ __align__(16) float s1o[16][264];
    __shared__ float wo1s[DIM];
    __shared__ int s_rdy;

    const int bid = blockIdx.x;
    int role, bg, p = 0;
    if (bid < 16)      { role = 0; bg = bid >> 2; p = bid & 3; }
    else if (bid < 20) { role = 1; bg = bid - 16; }
    else if (bid < 36) { role = 2; bg = (bid - 20) >> 2; p = (bid - 20) & 3; }
    else               { role = 3; bg = bid - 36; }

    const int lane = threadIdx.x & 63;
    const int l15 = lane & 15;
    const int b0 = bg * 16;

    // uniform tmax = max xlen over this bg's 16 rows (same in all stages)
    int v = xlen[b0 + l15];
#pragma unroll
    for (int o = 1; o < 16; o <<= 1) v = max(v, __shfl_xor(v, o));
    const int tmax = __builtin_amdgcn_readfirstlane(v);

    if (role == 0) {
        proj_body<1, 0>(x, wpW, XP, 0, bg, p, tmax, nullptr, flags + bg * 4 + p);
    } else if (role == 1) {
        scan_body<0, 1, 1>(XP, wpU, 0, bg, HN, xlen, xlab, Wo, out,
                           flags + bg * 4, flags + 16 + bg,
                           s1q, rsq, s1o, wo1s, &s_rdy, tmax);
    } else if (role == 2) {
        proj_body<0, 1>(HN, wpW, HP, 3, bg, p, tmax,
                        flags + 16 + bg, flags + 20 + bg * 4 + p);
    } else {
        scan_body<1, 1, 0>(HP, wpU, 3, bg, nullptr, xlen, xlab, Wo, out,
                           flags + 20 + bg * 4, nullptr,
                           s1q, rsq, s1o, wo1s, &s_rdy, tmax);
    }
}

extern "C" void kernel_launch(void* const* d_in, const int* in_sizes, int n_in,
                              void* d_out, int out_size, void* d_ws, size_t ws_size,
                              hipStream_t stream) {
    const float* x    = (const float*)d_in[0];
    const int*   xlen = (const int*)d_in[1];
    const float* xlab = (const float*)d_in[2];
    const float* Wz   = (const float*)d_in[3];
    const float* Uz   = (const float*)d_in[4];
    const float* Wr   = (const float*)d_in[5];
    const float* Ur   = (const float*)d_in[6];
    const float* Wh   = (const float*)d_in[7];
    const float* Uh   = (const float*)d_in[8];
    const float* Wo   = (const float*)d_in[9];
    float* out = (float*)d_out;

    unsigned char* ws  = (unsigned char*)d_ws;
    unsigned char* wpU = ws;                                 // fp8 U-frags, 384 KB
    unsigned char* wpW = ws + OFF_WPW;                       // bf16 W-frags, 768 KB
    int*           FLG = (int*)(ws + OFF_FLG);               // pipeline flags
    unsigned int*  XP  = (unsigned int*)(ws + OFF_XP);       // 25.2 MB
    unsigned int*  HP  = (unsigned int*)(ws + OFF_HP);       // 25.2 MB
    unsigned short* HN = (unsigned short*)(ws + OFF_HN);     // 16.8 MB

    // ws re-poisoned every call -> rebuild everything (incl. flags) each time.
    prep_weights<<<1536, 256, 0, stream>>>(Wz, Wr, Wh, Uz, Ur, Uh, ws, out);
    fused_pipeline<<<40, 1024, 0, stream>>>(x, XP, HP, wpU, wpW, HN,
                                            xlen, xlab, Wo, out, FLG);
}

// Round 4
// 1684.786 us; speedup vs baseline: 1.0670x; 1.0670x over previous
//
#include <hip/hip_runtime.h>

// Dims fixed by the reference
#define LAY 2
#define BATCH 64
#define TMAX 512
#define DIM 256
#define AST 264    // LDS activation row stride (bytes, fp8)
#define CHUNK 16   // pipeline handoff granularity (timesteps)

typedef float floatx4 __attribute__((ext_vector_type(4)));
typedef __bf16 bf16x8 __attribute__((ext_vector_type(8)));
#define MFMA_FP8  __builtin_amdgcn_mfma_f32_16x16x32_fp8_fp8
#define MFMA_BF16 __builtin_amdgcn_mfma_f32_16x16x32_bf16

// d_ws layout (requires ws >= ~74 MB)
#define OFF_WPW 0x60000     // bf16 B-frag W-mats, 6 x 128 KB  (ends 0x120000)
#define OFF_FLG 0x150000    // flags: [0..3] scan0, [4..19] projB
#define OFF_XP  0x200000    // layer-0 X-projections fp8, 25.2 MB
#define OFF_HP  0x1C00000   // layer-1 input projections fp8, 25.2 MB
#define OFF_HN  0x3600000   // hn0 bf16 [b*512+t][256], 16.8 MB

__device__ __forceinline__ unsigned short f2bf(float f) {
    unsigned int u = __float_as_uint(f);
    unsigned int r = u + 0x7fffu + ((u >> 16) & 1u);  // RNE
    return (unsigned short)(r >> 16);
}
__device__ __forceinline__ unsigned int pk2(float a, float b) {
    return (unsigned int)__builtin_amdgcn_cvt_pk_fp8_f32(a, b, 0, false);  // OCP e4m3 x2
}
__device__ __forceinline__ unsigned char f2q(float a) { return (unsigned char)(pk2(a, a) & 0xff); }
__device__ __forceinline__ void unp4(unsigned int u, float* f) {
    auto lo = __builtin_amdgcn_cvt_pk_f32_fp8((int)u, false);
    auto hi = __builtin_amdgcn_cvt_pk_f32_fp8((int)u, true);
    f[0] = lo[0]; f[1] = lo[1]; f[2] = hi[0]; f[3] = hi[1];
}
__device__ __forceinline__ float sigf(float x) { return 1.f / (1.f + __expf(-x)); }
// tanh(y) = 2*sigmoid(2y) - 1
__device__ __forceinline__ float tanhfast2y(float twoy) { return 2.f * sigf(twoy) - 1.f; }

// ---------------------------------------------------------------------------
// Weight prep (identical math). Zeroes 32 pipeline flags and d_out.
// ---------------------------------------------------------------------------
__global__ void prep_weights(const float* __restrict__ Wz, const float* __restrict__ Wr,
                             const float* __restrict__ Wh, const float* __restrict__ Uz,
                             const float* __restrict__ Ur, const float* __restrict__ Uh,
                             unsigned char* __restrict__ ws, float* __restrict__ out) {
    int T = blockIdx.x * 256 + threadIdx.x;  // 1536*256 = 393216
    if (T == 0) out[0] = 0.f;
    if (T < 32) ((int*)(ws + OFF_FLG))[T] = 0;   // pipeline flags (ws re-poisoned each call)
    if (T < 196608) {  // U-mats, fp8
        int e = T & 3, half = (T >> 2) & 1, lane = (T >> 3) & 63;
        int kp = (T >> 9) & 3, nt = (T >> 11) & 15, mu = T >> 15;
        int g = mu % 3, l = mu / 3;
        const float* s = (g == 0 ? Uz : g == 1 ? Ur : Uh) + l * 65536;
        int n  = nt * 16 + (lane & 15);
        int k0 = (2 * kp + half) * 32 + (lane >> 4) * 8 + 2 * e;
        float w0 = s[(k0 << 8) + n] * 8.f;        // x8: dodge e4m3 denormals
        float w1 = s[((k0 + 1) << 8) + n] * 8.f;  // undone by 0.125 post-acc
        int addr = ((mu * 16 + nt) * 4 + kp) * 1024 + lane * 16 + half * 8 + 2 * e;
        *(unsigned short*)(ws + addr) = (unsigned short)(pk2(w0, w1) & 0xffff);
    } else {           // W-mats, bf16
        int T2 = T - 196608;
        int e = T2 & 3, lane = (T2 >> 2) & 63;
        int kf = (T2 >> 8) & 7, nt = (T2 >> 11) & 15, mw = T2 >> 15;
        int g = mw % 3, l = mw / 3;
        const float* s = (g == 0 ? Wz : g == 1 ? Wr : Wh) + l * 65536;
        int n  = nt * 16 + (lane & 15);
        int k0 = kf * 32 + (lane >> 4) * 8 + 2 * e;
        unsigned int v = (unsigned int)f2bf(s[(k0 << 8) + n]) |
                         ((unsigned int)f2bf(s[((k0 + 1) << 8) + n]) << 16);
        int addr = ((mw * 16 + nt) * 8 + kf) * 1024 + lane * 16 + 4 * e;
        *(unsigned int*)(ws + OFF_WPW + addr) = v;
    }
}

// ---------------------------------------------------------------------------
// Stage-A projection GEMM (standalone, as R2): XP = x @ W(l0). Grid 2048.
// ---------------------------------------------------------------------------
template <int F32SRC>
__global__ __launch_bounds__(1024) void proj_kernel(const void* __restrict__ src,
                                                    const unsigned char* __restrict__ wpW,
                                                    unsigned int* __restrict__ xpo, int matbase) {
    const int bgt = blockIdx.x;
    const int t = bgt & 511, bg = bgt >> 9;
    const int tid = threadIdx.x, wave = tid >> 6, lane = tid & 63;
    const int l15 = lane & 15, quad = lane >> 4;
    const size_t rowoff = ((size_t)(bg * 16 + l15) * 512 + t) * 256;

    bf16x8 af[8];
    if (F32SRC) {
        const float* s = (const float*)src + rowoff;
#pragma unroll
        for (int kf = 0; kf < 8; ++kf) {
            float4 a = *(const float4*)(s + kf * 32 + quad * 8);
            float4 b = *(const float4*)(s + kf * 32 + quad * 8 + 4);
            union { unsigned short u[8]; bf16x8 v; } cv;
            cv.u[0] = f2bf(a.x); cv.u[1] = f2bf(a.y); cv.u[2] = f2bf(a.z); cv.u[3] = f2bf(a.w);
            cv.u[4] = f2bf(b.x); cv.u[5] = f2bf(b.y); cv.u[6] = f2bf(b.z); cv.u[7] = f2bf(b.w);
            af[kf] = cv.v;
        }
    } else {
        const unsigned short* s = (const unsigned short*)src + rowoff;
#pragma unroll
        for (int kf = 0; kf < 8; ++kf) af[kf] = *(const bf16x8*)(s + kf * 32 + quad * 8);
    }

    floatx4 az = {0.f, 0.f, 0.f, 0.f}, ar = az, ah = az;
    const unsigned char* bz = wpW + (size_t)(((matbase + 0) * 16 + wave) * 8) * 1024 + lane * 16;
    const unsigned char* br = wpW + (size_t)(((matbase + 1) * 16 + wave) * 8) * 1024 + lane * 16;
    const unsigned char* bh = wpW + (size_t)(((matbase + 2) * 16 + wave) * 8) * 1024 + lane * 16;
#pragma unroll
    for (int kf = 0; kf < 8; ++kf) {
        az = MFMA_BF16(af[kf], *(const bf16x8*)(bz + kf * 1024), az, 0, 0, 0);
        ar = MFMA_BF16(af[kf], *(const bf16x8*)(br + kf * 1024), ar, 0, 0, 0);
        ah = MFMA_BF16(af[kf], *(const bf16x8*)(bh + kf * 1024), ah, 0, 0, 0);
    }
    const size_t ob = (size_t)bgt * 3072 + wave * 64 + lane;
    xpo[ob]        = pk2(16.f * az[0], 16.f * az[1]) | (pk2(16.f * az[2], 16.f * az[3]) << 16);
    xpo[ob + 1024] = pk2(16.f * ar[0], 16.f * ar[1]) | (pk2(16.f * ar[2], 16.f * ar[3]) << 16);
    xpo[ob + 2048] = pk2(16.f * ah[0], 16.f * ah[1]) | (pk2(16.f * ah[2], 16.f * ah[3]) << 16);
}

// ---------------------------------------------------------------------------
// GRU scan body. WAIT==1: wait on MIN of 4 upstream flags. POST==1: publish
// pflag per CHUNK. Input projections register-prefetched one step ahead
// (clamped to the ready horizon) so HBM/IF$ latency stays off the critical
// path. MFMA accumulation chains split 2x to halve dep-latency.
// ---------------------------------------------------------------------------
template <int SCORE, int WAIT, int POST>
__device__ __forceinline__ void scan_body(
    const unsigned int* __restrict__ xp, const unsigned char* __restrict__ wpU,
    int lbase, int bg, unsigned short* __restrict__ hnout,
    const int* __restrict__ xlen, const float* __restrict__ xlab,
    const float* __restrict__ Wo, float* __restrict__ out,
    int* wflags, int* pflag,
    unsigned char (*s1q)[AST], unsigned char (*rsq)[AST], float (*s1o)[264],
    float* wo1s, int* s_rdy, int tmax)
{
    const int tid = threadIdx.x, wave = tid >> 6, lane = tid & 63;
    const int l15 = lane & 15, quad = lane >> 4;
    const int b0 = bg * 16;

    for (int i = tid; i < 16 * AST; i += 1024) ((unsigned char*)s1q)[i] = 0;
    if (SCORE && tid < DIM) wo1s[tid] = Wo[2 * tid + 1];
    const int lenr = xlen[b0 + l15];
    const float labr = SCORE ? xlab[b0 + l15] : 0.f;
    (void)lenr; (void)labr;

    const int nt = wave;
    const int colA = nt * 16 + l15, rowb = quad * 4;

    // register-resident U fragments for this wave's 16-col tile
    long uz[8], ur[8], uh[8];
    {
        const unsigned char* pz = wpU + (size_t)(((lbase + 0) * 16 + nt) * 4) * 1024 + lane * 16;
        const unsigned char* pr = wpU + (size_t)(((lbase + 1) * 16 + nt) * 4) * 1024 + lane * 16;
        const unsigned char* ph = wpU + (size_t)(((lbase + 2) * 16 + nt) * 4) * 1024 + lane * 16;
#pragma unroll
        for (int kf = 0; kf < 8; ++kf) {
            int o = (kf >> 1) * 1024 + (kf & 1) * 8;
            uz[kf] = *(const long*)(pz + o);
            ur[kf] = *(const long*)(pr + o);
            uh[kf] = *(const long*)(ph + o);
        }
    }
    float s1r[4] = {};
    float accl = 0.f;
    int ready = 0;
    unsigned int cz = 0, cr = 0, ch = 0;
    bool have = false;
    __syncthreads();

    for (int t = 0; t < tmax; ++t) {
        if (WAIT && t >= ready) {
            if (tid == 0) {
                int vv, g = 0;
                for (;;) {
                    int m0 = __hip_atomic_load(wflags + 0, __ATOMIC_RELAXED, __HIP_MEMORY_SCOPE_AGENT);
                    int m1 = __hip_atomic_load(wflags + 1, __ATOMIC_RELAXED, __HIP_MEMORY_SCOPE_AGENT);
                    int m2 = __hip_atomic_load(wflags + 2, __ATOMIC_RELAXED, __HIP_MEMORY_SCOPE_AGENT);
                    int m3 = __hip_atomic_load(wflags + 3, __ATOMIC_RELAXED, __HIP_MEMORY_SCOPE_AGENT);
                    int a = m0 < m1 ? m0 : m1, b = m2 < m3 ? m2 : m3;
                    vv = a < b ? a : b;
                    if (vv > t || ++g > (1 << 19)) break;   // fail visibly, never hang
                    __builtin_amdgcn_s_sleep(2);
                }
                __threadfence();          // agent acquire before data reads
                *s_rdy = vv > t ? vv : t + 1;
            }
            __syncthreads();
            ready = *s_rdy;
        }

        if (!have) {   // chunk boundary (or t=0): synchronous load of this step
            const unsigned int* xpt = xp + (size_t)(bg * 512 + t) * 3072 + lane;
            cz = xpt[nt * 64];
            cr = xpt[1024 + nt * 64];
            ch = xpt[2048 + nt * 64];
        }
        // prefetch next step if already published (hides HBM/IF$ latency)
        const int lim = WAIT ? (ready < tmax ? ready : tmax) : tmax;
        const bool pfn = (t + 1 < lim);
        unsigned int nz = 0, nr = 0, nh = 0;
        if (pfn) {
            const unsigned int* xpn = xp + (size_t)(bg * 512 + t + 1) * 3072 + lane;
            nz = xpn[nt * 64];
            nr = xpn[1024 + nt * 64];
            nh = xpn[2048 + nt * 64];
        }

        // ---- phase 1: r (critical path) + z-MFMAs (accs dangle, split 2x) ----
        long sf[8];
#pragma unroll
        for (int kf = 0; kf < 8; ++kf) sf[kf] = *(const long*)&s1q[l15][kf * 32 + quad * 8];
        floatx4 zer = {0.f, 0.f, 0.f, 0.f};
        floatx4 ra0 = zer, ra1 = zer, za0 = zer, za1 = zer;
#pragma unroll
        for (int kf = 0; kf < 4; ++kf) {
            ra0 = MFMA_FP8(sf[kf],     ur[kf],     ra0, 0, 0, 0);
            za0 = MFMA_FP8(sf[kf],     uz[kf],     za0, 0, 0, 0);
            ra1 = MFMA_FP8(sf[kf + 4], ur[kf + 4], ra1, 0, 0, 0);
            za1 = MFMA_FP8(sf[kf + 4], uz[kf + 4], za1, 0, 0, 0);
        }
        floatx4 ra = ra0 + ra1;
        float xrf[4];
        unp4(cr, xrf);
#pragma unroll
        for (int i = 0; i < 4; ++i) {
            float r = sigf(0.125f * ra[i] + 0.0625f * xrf[i]);
            rsq[rowb + i][colA] = f2q(r * s1r[i]);
        }
        __syncthreads();

        // ---- phase 2: h (split 2x); z-sigmoid overlaps the Uh MFMA ----
        long rf[8];
#pragma unroll
        for (int kf = 0; kf < 8; ++kf) rf[kf] = *(const long*)&rsq[l15][kf * 32 + quad * 8];
        floatx4 ha0 = zer, ha1 = zer;
#pragma unroll
        for (int kf = 0; kf < 4; ++kf) {
            ha0 = MFMA_FP8(rf[kf],     uh[kf],     ha0, 0, 0, 0);
            ha1 = MFMA_FP8(rf[kf + 4], uh[kf + 4], ha1, 0, 0, 0);
        }
        floatx4 ha = ha0 + ha1;
        floatx4 za = za0 + za1;
        float xzf[4], xhf[4];
        unp4(cz, xzf); unp4(ch, xhf);
#pragma unroll
        for (int i = 0; i < 4; ++i) {
            float z = sigf(0.125f * za[i] + 0.0625f * xzf[i]);
            float h = tanhfast2y(0.25f * ha[i] + 0.125f * xhf[i]);
            float hn = (1.f - z) * s1r[i] + z * h;
            s1r[i] = hn;
            s1q[rowb + i][colA] = f2q(hn);
            s1o[rowb + i][colA] = hn;
        }
        __syncthreads();

        if (!SCORE) {
            const int r = tid >> 6, c = (tid & 63) * 4;
            float4 f0 = *(const float4*)&s1o[r][c];
            uint2 o2;
            o2.x = f2bf(f0.x) | ((unsigned)f2bf(f0.y) << 16);
            o2.y = f2bf(f0.z) | ((unsigned)f2bf(f0.w) << 16);
            *(uint2*)(hnout + ((size_t)(b0 + r) * 512 + t) * 256 + c) = o2;
        } else if (wave == 0) {
            const int row = l15, c0 = quad * 64;
            float p = 0.f;
#pragma unroll
            for (int u = 0; u < 64; u += 4) {
                float4 sv = *(const float4*)&s1o[row][c0 + u];
                float4 wv = *(const float4*)&wo1s[c0 + u];
                p = fmaf(sv.x, wv.x, p); p = fmaf(sv.y, wv.y, p);
                p = fmaf(sv.z, wv.z, p); p = fmaf(sv.w, wv.w, p);
            }
            p += __shfl_xor(p, 16);
            p += __shfl_xor(p, 32);
            if (lane < 16 && t < lenr) {
                float sc = sigf(p);
                float d = labr - sc;
                accl = fmaf(d, d, accl);
            }
        }

        if (POST && (((t & (CHUNK - 1)) == (CHUNK - 1)) || t == tmax - 1)) {
            __syncthreads();   // all waves' HN stores drained (vmcnt0 before barrier)
            if (tid == 0) {
                __threadfence();   // agent release: push chunk data to coherent point
                __hip_atomic_store(pflag, t + 1, __ATOMIC_RELEASE, __HIP_MEMORY_SCOPE_AGENT);
            }
        }

        cz = nz; cr = nr; ch = nh; have = pfn;
    }

    if (SCORE && wave == 0) {
        accl += __shfl_xor(accl, 1);
        accl += __shfl_xor(accl, 2);
        accl += __shfl_xor(accl, 4);
        accl += __shfl_xor(accl, 8);
        if (lane == 0) atomicAdd(out, accl);
    }
}

// ---------------------------------------------------------------------------
// Fused 3-stage pipeline, 24 WGs (R2 topology):
//   blocks 0-3  : layer-0 scan (posts flags[bg] per chunk)
//   blocks 4-19 : projB, 4 WGs per bg; WG p owns t in [base+4p, base+4p+4) of
//                 each chunk; waits flags[bg], posts flags[4+bg*4+p]
//   blocks 20-23: layer-1 scan + loss (waits MIN of the bg's 4 projB flags)
// ---------------------------------------------------------------------------
__global__ __launch_bounds__(1024, 4) void fused_pipeline(
    const unsigned int* __restrict__ XP, unsigned int* __restrict__ HP,
    const unsigned char* __restrict__ wpU, const unsigned char* __restrict__ wpW,
    unsigned short* __restrict__ HN,
    const int* __restrict__ xlen, const float* __restrict__ xlab,
    const float* __restrict__ Wo, float* __restrict__ out, int* flags)
{
    __shared__ __align__(16) unsigned char s1q[16][AST];
    __shared__ __align__(16) unsigned char rsq[16][AST];
    __shared__ __align__(16) float s1o[16][264];
    __shared__ float wo1s[DIM];
    __shared__ int s_rdy;

    const int bid = blockIdx.x;
    int role, bg, p = 0;
    if (bid < 4)       { role = 0; bg = bid; }
    else if (bid < 20) { role = 1; bg = (bid - 4) >> 2; p = (bid - 4) & 3; }
    else               { role = 2; bg = bid - 20; }

    const int tid = threadIdx.x, wave = tid >> 6, lane = tid & 63;
    const int l15 = lane & 15, quad = lane >> 4;
    const int b0 = bg * 16;

    // uniform tmax = max xlen over this bg's 16 rows (same in all stages)
    int v = xlen[b0 + l15];
#pragma unroll
    for (int o = 1; o < 16; o <<= 1) v = max(v, __shfl_xor(v, o));
    const int tmax = __builtin_amdgcn_readfirstlane(v);

    if (role == 0) {
        scan_body<0, 0, 1>(XP, wpU, 0, bg, HN, xlen, xlab, Wo, out,
                           nullptr, flags + bg, s1q, rsq, s1o, wo1s, &s_rdy, tmax);
    } else if (role == 2) {
        scan_body<1, 1, 0>(HP, wpU, 3, bg, nullptr, xlen, xlab, Wo, out,
                           flags + 4 + bg * 4, nullptr, s1q, rsq, s1o, wo1s, &s_rdy, tmax);
    } else {
        // ---- projB stage: HP[t] = HN[t] @ W(l1); this WG owns 4 t per chunk ----
        int* wf = flags + bg;
        int* pf = flags + 4 + bg * 4 + p;
        const unsigned char* bz = wpW + (size_t)(((3 + 0) * 16 + wave) * 8) * 1024 + lane * 16;
        const unsigned char* br = wpW + (size_t)(((3 + 1) * 16 + wave) * 8) * 1024 + lane * 16;
        const unsigned char* bh = wpW + (size_t)(((3 + 2) * 16 + wave) * 8) * 1024 + lane * 16;
        for (int base = 0; base < tmax; base += CHUNK) {
            const int target = (base + CHUNK < tmax) ? base + CHUNK : tmax;
            if (tid == 0) {
                int vv, g = 0;
                for (;;) {
                    vv = __hip_atomic_load(wf, __ATOMIC_RELAXED, __HIP_MEMORY_SCOPE_AGENT);
                    if (vv >= target || ++g > (1 << 19)) break;
                    __builtin_amdgcn_s_sleep(2);
                }
                __threadfence();   // acquire: see scan0's HN chunk
            }
            __syncthreads();       // no wave reads HN before the inv

            const int t0 = base + p * 4;
            const int t1 = (t0 + 4 < tmax) ? t0 + 4 : tmax;
            for (int t = t0; t < t1; ++t) {
                const unsigned short* sA = HN + ((size_t)(b0 + l15) * 512 + t) * 256;
                bf16x8 af[8];
#pragma unroll
                for (int kf = 0; kf < 8; ++kf) af[kf] = *(const bf16x8*)(sA + kf * 32 + quad * 8);
                floatx4 az = {0.f, 0.f, 0.f, 0.f}, ar = az, ah = az;
#pragma unroll
                for (int kf = 0; kf < 8; ++kf) {
                    az = MFMA_BF16(af[kf], *(const bf16x8*)(bz + kf * 1024), az, 0, 0, 0);
                    ar = MFMA_BF16(af[kf], *(const bf16x8*)(br + kf * 1024), ar, 0, 0, 0);
                    ah = MFMA_BF16(af[kf], *(const bf16x8*)(bh + kf * 1024), ah, 0, 0, 0);
                }
                const size_t ob = (size_t)(bg * 512 + t) * 3072 + wave * 64 + lane;
                HP[ob]        = pk2(16.f * az[0], 16.f * az[1]) | (pk2(16.f * az[2], 16.f * az[3]) << 16);
                HP[ob + 1024] = pk2(16.f * ar[0], 16.f * ar[1]) | (pk2(16.f * ar[2], 16.f * ar[3]) << 16);
                HP[ob + 2048] = pk2(16.f * ah[0], 16.f * ah[1]) | (pk2(16.f * ah[2], 16.f * ah[3]) << 16);
            }

            __syncthreads();   // all waves' HP stores drained (vmcnt0 before barrier)
            if (tid == 0) {
                __threadfence();   // release: push HP chunk to coherent point
                __hip_atomic_store(pf, base + CHUNK, __ATOMIC_RELEASE, __HIP_MEMORY_SCOPE_AGENT);
            }
        }
    }
}

extern "C" void kernel_launch(void* const* d_in, const int* in_sizes, int n_in,
                              void* d_out, int out_size, void* d_ws, size_t ws_size,
                              hipStream_t stream) {
    const float* x    = (const float*)d_in[0];
    const int*   xlen = (const int*)d_in[1];
    const float* xlab = (const float*)d_in[2];
    const float* Wz   = (const float*)d_in[3];
    const float* Uz   = (const float*)d_in[4];
    const float* Wr   = (const float*)d_in[5];
    const float* Ur   = (const float*)d_in[6];
    const float* Wh   = (const float*)d_in[7];
    const float* Uh   = (const float*)d_in[8];
    const float* Wo   = (const float*)d_in[9];
    float* out = (float*)d_out;

    unsigned char* ws  = (unsigned char*)d_ws;
    unsigned char* wpU = ws;                                 // fp8 U-frags, 384 KB
    unsigned char* wpW = ws + OFF_WPW;                       // bf16 W-frags, 768 KB
    int*           FLG = (int*)(ws + OFF_FLG);               // pipeline flags
    unsigned int*  XP  = (unsigned int*)(ws + OFF_XP);       // 25.2 MB
    unsigned int*  HP  = (unsigned int*)(ws + OFF_HP);       // 25.2 MB
    unsigned short* HN = (unsigned short*)(ws + OFF_HN);     // 16.8 MB

    // ws re-poisoned every call -> rebuild everything (incl. flags) each time.
    prep_weights<<<1536, 256, 0, stream>>>(Wz, Wr, Wh, Uz, Ur, Uh, ws, out);
    proj_kernel<1><<<2048, 1024, 0, stream>>>(x, wpW, XP, 0);   // A: x @ W(l0)
    fused_pipeline<<<24, 1024, 0, stream>>>(XP, HP, wpU, wpW, HN,
                                            xlen, xlab, Wo, out, FLG);
}

// Round 5
// 1633.870 us; speedup vs baseline: 1.1003x; 1.0312x over previous
//
#include <hip/hip_runtime.h>

// Dims fixed by the reference
#define LAY 2
#define BATCH 64
#define TMAX 512
#define DIM 256
#define AST 264    // LDS activation row stride (bytes, fp8)
#define CHUNK 16   // pipeline handoff granularity (timesteps)

typedef float floatx4 __attribute__((ext_vector_type(4)));
typedef __bf16 bf16x8 __attribute__((ext_vector_type(8)));
#define MFMA_FP8  __builtin_amdgcn_mfma_f32_16x16x32_fp8_fp8
#define MFMA_BF16 __builtin_amdgcn_mfma_f32_16x16x32_bf16

// LDS-only barrier: orders ds ops (lgkmcnt) without draining vmcnt, so
// in-flight global loads/stores (XP/HP loads, HN stores) stay outstanding
// across the per-step barriers. "memory" clobber pins ds ops to their side.
#define BAR_LDS() asm volatile("s_waitcnt lgkmcnt(0)\n\ts_barrier" ::: "memory")

// d_ws layout (requires ws >= ~74 MB)
#define OFF_WPW 0x60000     // bf16 B-frag W-mats, 6 x 128 KB  (ends 0x120000)
#define OFF_FLG 0x150000    // flags: [0..3] scan0, [4..19] projB
#define OFF_XP  0x200000    // layer-0 X-projections fp8, 25.2 MB
#define OFF_HP  0x1C00000   // layer-1 input projections fp8, 25.2 MB
#define OFF_HN  0x3600000   // hn0 bf16 [b*512+t][256], 16.8 MB

__device__ __forceinline__ unsigned short f2bf(float f) {
    unsigned int u = __float_as_uint(f);
    unsigned int r = u + 0x7fffu + ((u >> 16) & 1u);  // RNE
    return (unsigned short)(r >> 16);
}
__device__ __forceinline__ unsigned int pk2(float a, float b) {
    return (unsigned int)__builtin_amdgcn_cvt_pk_fp8_f32(a, b, 0, false);  // OCP e4m3 x2
}
__device__ __forceinline__ unsigned char f2q(float a) { return (unsigned char)(pk2(a, a) & 0xff); }
__device__ __forceinline__ void unp4(unsigned int u, float* f) {
    auto lo = __builtin_amdgcn_cvt_pk_f32_fp8((int)u, false);
    auto hi = __builtin_amdgcn_cvt_pk_f32_fp8((int)u, true);
    f[0] = lo[0]; f[1] = lo[1]; f[2] = hi[0]; f[3] = hi[1];
}
__device__ __forceinline__ float sigf(float x) { return 1.f / (1.f + __expf(-x)); }
// tanh(y) = 2*sigmoid(2y) - 1
__device__ __forceinline__ float tanhfast2y(float twoy) { return 2.f * sigf(twoy) - 1.f; }

// ---------------------------------------------------------------------------
// Weight prep (identical math). Zeroes 32 pipeline flags and d_out.
// ---------------------------------------------------------------------------
__global__ void prep_weights(const float* __restrict__ Wz, const float* __restrict__ Wr,
                             const float* __restrict__ Wh, const float* __restrict__ Uz,
                             const float* __restrict__ Ur, const float* __restrict__ Uh,
                             unsigned char* __restrict__ ws, float* __restrict__ out) {
    int T = blockIdx.x * 256 + threadIdx.x;  // 1536*256 = 393216
    if (T == 0) out[0] = 0.f;
    if (T < 32) ((int*)(ws + OFF_FLG))[T] = 0;   // pipeline flags (ws re-poisoned each call)
    if (T < 196608) {  // U-mats, fp8
        int e = T & 3, half = (T >> 2) & 1, lane = (T >> 3) & 63;
        int kp = (T >> 9) & 3, nt = (T >> 11) & 15, mu = T >> 15;
        int g = mu % 3, l = mu / 3;
        const float* s = (g == 0 ? Uz : g == 1 ? Ur : Uh) + l * 65536;
        int n  = nt * 16 + (lane & 15);
        int k0 = (2 * kp + half) * 32 + (lane >> 4) * 8 + 2 * e;
        float w0 = s[(k0 << 8) + n] * 8.f;        // x8: dodge e4m3 denormals
        float w1 = s[((k0 + 1) << 8) + n] * 8.f;  // undone by 0.125 post-acc
        int addr = ((mu * 16 + nt) * 4 + kp) * 1024 + lane * 16 + half * 8 + 2 * e;
        *(unsigned short*)(ws + addr) = (unsigned short)(pk2(w0, w1) & 0xffff);
    } else {           // W-mats, bf16
        int T2 = T - 196608;
        int e = T2 & 3, lane = (T2 >> 2) & 63;
        int kf = (T2 >> 8) & 7, nt = (T2 >> 11) & 15, mw = T2 >> 15;
        int g = mw % 3, l = mw / 3;
        const float* s = (g == 0 ? Wz : g == 1 ? Wr : Wh) + l * 65536;
        int n  = nt * 16 + (lane & 15);
        int k0 = kf * 32 + (lane >> 4) * 8 + 2 * e;
        unsigned int v = (unsigned int)f2bf(s[(k0 << 8) + n]) |
                         ((unsigned int)f2bf(s[((k0 + 1) << 8) + n]) << 16);
        int addr = ((mw * 16 + nt) * 8 + kf) * 1024 + lane * 16 + 4 * e;
        *(unsigned int*)(ws + OFF_WPW + addr) = v;
    }
}

// ---------------------------------------------------------------------------
// Stage-A projection GEMM (standalone): XP = x @ W(l0). Grid 2048.
// ---------------------------------------------------------------------------
template <int F32SRC>
__global__ __launch_bounds__(1024) void proj_kernel(const void* __restrict__ src,
                                                    const unsigned char* __restrict__ wpW,
                                                    unsigned int* __restrict__ xpo, int matbase) {
    const int bgt = blockIdx.x;
    const int t = bgt & 511, bg = bgt >> 9;
    const int tid = threadIdx.x, wave = tid >> 6, lane = tid & 63;
    const int l15 = lane & 15, quad = lane >> 4;
    const size_t rowoff = ((size_t)(bg * 16 + l15) * 512 + t) * 256;

    bf16x8 af[8];
    if (F32SRC) {
        const float* s = (const float*)src + rowoff;
#pragma unroll
        for (int kf = 0; kf < 8; ++kf) {
            float4 a = *(const float4*)(s + kf * 32 + quad * 8);
            float4 b = *(const float4*)(s + kf * 32 + quad * 8 + 4);
            union { unsigned short u[8]; bf16x8 v; } cv;
            cv.u[0] = f2bf(a.x); cv.u[1] = f2bf(a.y); cv.u[2] = f2bf(a.z); cv.u[3] = f2bf(a.w);
            cv.u[4] = f2bf(b.x); cv.u[5] = f2bf(b.y); cv.u[6] = f2bf(b.z); cv.u[7] = f2bf(b.w);
            af[kf] = cv.v;
        }
    } else {
        const unsigned short* s = (const unsigned short*)src + rowoff;
#pragma unroll
        for (int kf = 0; kf < 8; ++kf) af[kf] = *(const bf16x8*)(s + kf * 32 + quad * 8);
    }

    floatx4 az = {0.f, 0.f, 0.f, 0.f}, ar = az, ah = az;
    const unsigned char* bz = wpW + (size_t)(((matbase + 0) * 16 + wave) * 8) * 1024 + lane * 16;
    const unsigned char* br = wpW + (size_t)(((matbase + 1) * 16 + wave) * 8) * 1024 + lane * 16;
    const unsigned char* bh = wpW + (size_t)(((matbase + 2) * 16 + wave) * 8) * 1024 + lane * 16;
#pragma unroll
    for (int kf = 0; kf < 8; ++kf) {
        az = MFMA_BF16(af[kf], *(const bf16x8*)(bz + kf * 1024), az, 0, 0, 0);
        ar = MFMA_BF16(af[kf], *(const bf16x8*)(br + kf * 1024), ar, 0, 0, 0);
        ah = MFMA_BF16(af[kf], *(const bf16x8*)(bh + kf * 1024), ah, 0, 0, 0);
    }
    const size_t ob = (size_t)bgt * 3072 + wave * 64 + lane;
    xpo[ob]        = pk2(16.f * az[0], 16.f * az[1]) | (pk2(16.f * az[2], 16.f * az[3]) << 16);
    xpo[ob + 1024] = pk2(16.f * ar[0], 16.f * ar[1]) | (pk2(16.f * ar[2], 16.f * ar[3]) << 16);
    xpo[ob + 2048] = pk2(16.f * ah[0], 16.f * ah[1]) | (pk2(16.f * ah[2], 16.f * ah[3]) << 16);
}

// ---------------------------------------------------------------------------
// GRU scan body (R2 math). WAIT==1: wait on MIN of 4 upstream flags.
// POST==1: publish pflag per CHUNK. Per-step barriers are LDS-only
// (BAR_LDS): no vmcnt drain -> XP/HP loads and HN stores stay in flight.
// Full __syncthreads only at WAIT/POST chunk boundaries.
// ---------------------------------------------------------------------------
template <int SCORE, int WAIT, int POST>
__device__ __forceinline__ void scan_body(
    const unsigned int* __restrict__ xp, const unsigned char* __restrict__ wpU,
    int lbase, int bg, unsigned short* __restrict__ hnout,
    const int* __restrict__ xlen, const float* __restrict__ xlab,
    const float* __restrict__ Wo, float* __restrict__ out,
    int* wflags, int* pflag,
    unsigned char (*s1q)[AST], unsigned char (*rsq)[AST], float (*s1o)[264],
    float* wo1s, int* s_rdy, int tmax)
{
    const int tid = threadIdx.x, wave = tid >> 6, lane = tid & 63;
    const int l15 = lane & 15, quad = lane >> 4;
    const int b0 = bg * 16;

    for (int i = tid; i < 16 * AST; i += 1024) ((unsigned char*)s1q)[i] = 0;
    if (SCORE && tid < DIM) wo1s[tid] = Wo[2 * tid + 1];
    const int lenr = xlen[b0 + l15];
    const float labr = SCORE ? xlab[b0 + l15] : 0.f;
    (void)lenr; (void)labr;

    const int nt = wave;
    const int colA = nt * 16 + l15, rowb = quad * 4;

    // register-resident U fragments for this wave's 16-col tile
    long uz[8], ur[8], uh[8];
    {
        const unsigned char* pz = wpU + (size_t)(((lbase + 0) * 16 + nt) * 4) * 1024 + lane * 16;
        const unsigned char* pr = wpU + (size_t)(((lbase + 1) * 16 + nt) * 4) * 1024 + lane * 16;
        const unsigned char* ph = wpU + (size_t)(((lbase + 2) * 16 + nt) * 4) * 1024 + lane * 16;
#pragma unroll
        for (int kf = 0; kf < 8; ++kf) {
            int o = (kf >> 1) * 1024 + (kf & 1) * 8;
            uz[kf] = *(const long*)(pz + o);
            ur[kf] = *(const long*)(pr + o);
            uh[kf] = *(const long*)(ph + o);
        }
    }
    float s1r[4] = {};
    float accl = 0.f;
    int ready = 0;
    __syncthreads();

    for (int t = 0; t < tmax; ++t) {
        if (WAIT && t >= ready) {
            if (tid == 0) {
                int vv, g = 0;
                for (;;) {
                    int m0 = __hip_atomic_load(wflags + 0, __ATOMIC_RELAXED, __HIP_MEMORY_SCOPE_AGENT);
                    int m1 = __hip_atomic_load(wflags + 1, __ATOMIC_RELAXED, __HIP_MEMORY_SCOPE_AGENT);
                    int m2 = __hip_atomic_load(wflags + 2, __ATOMIC_RELAXED, __HIP_MEMORY_SCOPE_AGENT);
                    int m3 = __hip_atomic_load(wflags + 3, __ATOMIC_RELAXED, __HIP_MEMORY_SCOPE_AGENT);
                    int a = m0 < m1 ? m0 : m1, b = m2 < m3 ? m2 : m3;
                    vv = a < b ? a : b;
                    if (vv > t || ++g > (1 << 19)) break;   // fail visibly, never hang
                    __builtin_amdgcn_s_sleep(2);
                }
                __threadfence();          // agent acquire before data reads
                *s_rdy = vv > t ? vv : t + 1;
            }
            __syncthreads();
            ready = *s_rdy;
        }

        const unsigned int* xpt = xp + (size_t)(bg * 512 + t) * 3072 + lane;
        unsigned int xz = xpt[nt * 64];
        unsigned int xr = xpt[1024 + nt * 64];
        unsigned int xh = xpt[2048 + nt * 64];

        // ---- phase 1: r (on the critical path) + z-MFMAs (acc dangles) ----
        long sf[8];
#pragma unroll
        for (int kf = 0; kf < 8; ++kf) sf[kf] = *(const long*)&s1q[l15][kf * 32 + quad * 8];
        floatx4 za = {0.f, 0.f, 0.f, 0.f}, ra = za;
#pragma unroll
        for (int kf = 0; kf < 8; ++kf) {
            ra = MFMA_FP8(sf[kf], ur[kf], ra, 0, 0, 0);
            za = MFMA_FP8(sf[kf], uz[kf], za, 0, 0, 0);
        }
        float xrf[4];
        unp4(xr, xrf);
#pragma unroll
        for (int i = 0; i < 4; ++i) {
            float r = sigf(0.125f * ra[i] + 0.0625f * xrf[i]);
            rsq[rowb + i][colA] = f2q(r * s1r[i]);
        }
        BAR_LDS();   // LDS-only: XP loads / HN stores stay in flight

        // ---- phase 2: h; z-sigmoid overlaps the Uh MFMA ----
        long rf[8];
#pragma unroll
        for (int kf = 0; kf < 8; ++kf) rf[kf] = *(const long*)&rsq[l15][kf * 32 + quad * 8];
        floatx4 ha = {0.f, 0.f, 0.f, 0.f};
#pragma unroll
        for (int kf = 0; kf < 8; ++kf) ha = MFMA_FP8(rf[kf], uh[kf], ha, 0, 0, 0);
        float xzf[4], xhf[4];
        unp4(xz, xzf); unp4(xh, xhf);
#pragma unroll
        for (int i = 0; i < 4; ++i) {
            float z = sigf(0.125f * za[i] + 0.0625f * xzf[i]);
            float h = tanhfast2y(0.25f * ha[i] + 0.125f * xhf[i]);  // tanh(0.125ha+0.0625xh)
            float hn = (1.f - z) * s1r[i] + z * h;
            s1r[i] = hn;
            s1q[rowb + i][colA] = f2q(hn);
            s1o[rowb + i][colA] = hn;
        }
        BAR_LDS();   // LDS-only

        if (!SCORE) {
            // cooperative hn0 write: row=tid>>6, 4 cols/thread; coalesced 8B stores
            const int r = tid >> 6, c = (tid & 63) * 4;
            float4 f0 = *(const float4*)&s1o[r][c];
            uint2 o2;
            o2.x = f2bf(f0.x) | ((unsigned)f2bf(f0.y) << 16);
            o2.y = f2bf(f0.z) | ((unsigned)f2bf(f0.w) << 16);
            *(uint2*)(hnout + ((size_t)(b0 + r) * 512 + t) * 256 + c) = o2;
        } else if (wave == 0) {
            const int row = l15, c0 = quad * 64;
            float p = 0.f;
#pragma unroll
            for (int u = 0; u < 64; u += 4) {
                float4 sv = *(const float4*)&s1o[row][c0 + u];
                float4 wv = *(const float4*)&wo1s[c0 + u];
                p = fmaf(sv.x, wv.x, p); p = fmaf(sv.y, wv.y, p);
                p = fmaf(sv.z, wv.z, p); p = fmaf(sv.w, wv.w, p);
            }
            p += __shfl_xor(p, 16);
            p += __shfl_xor(p, 32);
            if (lane < 16 && t < lenr) {
                float sc = sigf(p);
                float d = labr - sc;
                accl = fmaf(d, d, accl);
            }
        }

        if (POST && (((t & (CHUNK - 1)) == (CHUNK - 1)) || t == tmax - 1)) {
            __syncthreads();   // FULL drain: all waves' HN stores (vmcnt0) before fence
            if (tid == 0) {
                __threadfence();   // agent release: push chunk data to coherent point
                __hip_atomic_store(pflag, t + 1, __ATOMIC_RELEASE, __HIP_MEMORY_SCOPE_AGENT);
            }
        }
    }

    if (SCORE && wave == 0) {
        accl += __shfl_xor(accl, 1);
        accl += __shfl_xor(accl, 2);
        accl += __shfl_xor(accl, 4);
        accl += __shfl_xor(accl, 8);
        if (lane == 0) atomicAdd(out, accl);
    }
}

// ---------------------------------------------------------------------------
// Fused 3-stage pipeline, 24 WGs (R2 topology):
//   blocks 0-3  : layer-0 scan (posts flags[bg] per chunk)
//   blocks 4-19 : projB, 4 WGs per bg; WG p owns t in [base+4p, base+4p+4) of
//                 each chunk; waits flags[bg], posts flags[4+bg*4+p]
//   blocks 20-23: layer-1 scan + loss (waits MIN of the bg's 4 projB flags)
// ---------------------------------------------------------------------------
__global__ __launch_bounds__(1024, 4) void fused_pipeline(
    const unsigned int* __restrict__ XP, unsigned int* __restrict__ HP,
    const unsigned char* __restrict__ wpU, const unsigned char* __restrict__ wpW,
    unsigned short* __restrict__ HN,
    const int* __restrict__ xlen, const float* __restrict__ xlab,
    const float* __restrict__ Wo, float* __restrict__ out, int* flags)
{
    __shared__ __align__(16) unsigned char s1q[16][AST];
    __shared__ __align__(16) unsigned char rsq[16][AST];
    __shared__ __align__(16) float s1o[16][264];
    __shared__ float wo1s[DIM];
    __shared__ int s_rdy;

    const int bid = blockIdx.x;
    int role, bg, p = 0;
    if (bid < 4)       { role = 0; bg = bid; }
    else if (bid < 20) { role = 1; bg = (bid - 4) >> 2; p = (bid - 4) & 3; }
    else               { role = 2; bg = bid - 20; }

    const int tid = threadIdx.x, wave = tid >> 6, lane = tid & 63;
    const int l15 = lane & 15, quad = lane >> 4;
    const int b0 = bg * 16;

    // uniform tmax = max xlen over this bg's 16 rows (same in all stages)
    int v = xlen[b0 + l15];
#pragma unroll
    for (int o = 1; o < 16; o <<= 1) v = max(v, __shfl_xor(v, o));
    const int tmax = __builtin_amdgcn_readfirstlane(v);

    if (role == 0) {
        scan_body<0, 0, 1>(XP, wpU, 0, bg, HN, xlen, xlab, Wo, out,
                           nullptr, flags + bg, s1q, rsq, s1o, wo1s, &s_rdy, tmax);
    } else if (role == 2) {
        scan_body<1, 1, 0>(HP, wpU, 3, bg, nullptr, xlen, xlab, Wo, out,
                           flags + 4 + bg * 4, nullptr, s1q, rsq, s1o, wo1s, &s_rdy, tmax);
    } else {
        // ---- projB stage: HP[t] = HN[t] @ W(l1); this WG owns 4 t per chunk ----
        int* wf = flags + bg;
        int* pf = flags + 4 + bg * 4 + p;
        const unsigned char* bz = wpW + (size_t)(((3 + 0) * 16 + wave) * 8) * 1024 + lane * 16;
        const unsigned char* br = wpW + (size_t)(((3 + 1) * 16 + wave) * 8) * 1024 + lane * 16;
        const unsigned char* bh = wpW + (size_t)(((3 + 2) * 16 + wave) * 8) * 1024 + lane * 16;
        for (int base = 0; base < tmax; base += CHUNK) {
            const int target = (base + CHUNK < tmax) ? base + CHUNK : tmax;
            if (tid == 0) {
                int vv, g = 0;
                for (;;) {
                    vv = __hip_atomic_load(wf, __ATOMIC_RELAXED, __HIP_MEMORY_SCOPE_AGENT);
                    if (vv >= target || ++g > (1 << 19)) break;
                    __builtin_amdgcn_s_sleep(2);
                }
                __threadfence();   // acquire: see scan0's HN chunk
            }
            __syncthreads();       // no wave reads HN before the inv

            const int t0 = base + p * 4;
            const int t1 = (t0 + 4 < tmax) ? t0 + 4 : tmax;
            for (int t = t0; t < t1; ++t) {
                const unsigned short* sA = HN + ((size_t)(b0 + l15) * 512 + t) * 256;
                bf16x8 af[8];
#pragma unroll
                for (int kf = 0; kf < 8; ++kf) af[kf] = *(const bf16x8*)(sA + kf * 32 + quad * 8);
                floatx4 az = {0.f, 0.f, 0.f, 0.f}, ar = az, ah = az;
#pragma unroll
                for (int kf = 0; kf < 8; ++kf) {
                    az = MFMA_BF16(af[kf], *(const bf16x8*)(bz + kf * 1024), az, 0, 0, 0);
                    ar = MFMA_BF16(af[kf], *(const bf16x8*)(br + kf * 1024), ar, 0, 0, 0);
                    ah = MFMA_BF16(af[kf], *(const bf16x8*)(bh + kf * 1024), ah, 0, 0, 0);
                }
                const size_t ob = (size_t)(bg * 512 + t) * 3072 + wave * 64 + lane;
                HP[ob]        = pk2(16.f * az[0], 16.f * az[1]) | (pk2(16.f * az[2], 16.f * az[3]) << 16);
                HP[ob + 1024] = pk2(16.f * ar[0], 16.f * ar[1]) | (pk2(16.f * ar[2], 16.f * ar[3]) << 16);
                HP[ob + 2048] = pk2(16.f * ah[0], 16.f * ah[1]) | (pk2(16.f * ah[2], 16.f * ah[3]) << 16);
            }

            __syncthreads();   // all waves' HP stores drained (vmcnt0 before barrier)
            if (tid == 0) {
                __threadfence();   // release: push HP chunk to coherent point
                __hip_atomic_store(pf, base + CHUNK, __ATOMIC_RELEASE, __HIP_MEMORY_SCOPE_AGENT);
            }
        }
    }
}

extern "C" void kernel_launch(void* const* d_in, const int* in_sizes, int n_in,
                              void* d_out, int out_size, void* d_ws, size_t ws_size,
                              hipStream_t stream) {
    const float* x    = (const float*)d_in[0];
    const int*   xlen = (const int*)d_in[1];
    const float* xlab = (const float*)d_in[2];
    const float* Wz   = (const float*)d_in[3];
    const float* Uz   = (const float*)d_in[4];
    const float* Wr   = (const float*)d_in[5];
    const float* Ur   = (const float*)d_in[6];
    const float* Wh   = (const float*)d_in[7];
    const float* Uh   = (const float*)d_in[8];
    const float* Wo   = (const float*)d_in[9];
    float* out = (float*)d_out;

    unsigned char* ws  = (unsigned char*)d_ws;
    unsigned char* wpU = ws;                                 // fp8 U-frags, 384 KB
    unsigned char* wpW = ws + OFF_WPW;                       // bf16 W-frags, 768 KB
    int*           FLG = (int*)(ws + OFF_FLG);               // pipeline flags
    unsigned int*  XP  = (unsigned int*)(ws + OFF_XP);       // 25.2 MB
    unsigned int*  HP  = (unsigned int*)(ws + OFF_HP);       // 25.2 MB
    unsigned short* HN = (unsigned short*)(ws + OFF_HN);     // 16.8 MB

    // ws re-poisoned every call -> rebuild everything (incl. flags) each time.
    prep_weights<<<1536, 256, 0, stream>>>(Wz, Wr, Wh, Uz, Ur, Uh, ws, out);
    proj_kernel<1><<<2048, 1024, 0, stream>>>(x, wpW, XP, 0);   // A: x @ W(l0)
    fused_pipeline<<<24, 1024, 0, stream>>>(XP, HP, wpU, wpW, HN,
                                            xlen, xlab, Wo, out, FLG);
}

// Round 6
// 1290.688 us; speedup vs baseline: 1.3928x; 1.2659x over previous
//
#include <hip/hip_runtime.h>

// Dims fixed by the reference
#define LAY 2
#define BATCH 64
#define TMAX 512
#define DIM 256
#define AST 264    // LDS activation row stride (bytes, fp8)
#define CHUNK 16   // pipeline handoff granularity (timesteps)

typedef float floatx4 __attribute__((ext_vector_type(4)));
typedef __bf16 bf16x8 __attribute__((ext_vector_type(8)));
#define MFMA_FP8  __builtin_amdgcn_mfma_f32_16x16x32_fp8_fp8
#define MFMA_BF16 __builtin_amdgcn_mfma_f32_16x16x32_bf16

// LDS-only barrier: orders ds ops (lgkmcnt) without draining vmcnt, so
// in-flight global loads/stores (XP/HP loads, HN stores) stay outstanding
// across the per-step barriers. "memory" clobber pins ds ops to their side.
#define BAR_LDS() asm volatile("s_waitcnt lgkmcnt(0)\n\ts_barrier" ::: "memory")

// d_ws layout (requires ws >= ~74 MB)
#define OFF_WPW 0x60000     // bf16 B-frag W-mats, 6 x 128 KB  (ends 0x120000)
#define OFF_FLG 0x150000    // flags: [0..3] scan0, [4..19] projB
#define OFF_XP  0x200000    // layer-0 X-projections fp8, 25.2 MB
#define OFF_HP  0x1C00000   // layer-1 input projections fp8, 25.2 MB
#define OFF_HN  0x3600000   // hn0 bf16 [b*512+t][256], 16.8 MB

__device__ __forceinline__ unsigned short f2bf(float f) {
    unsigned int u = __float_as_uint(f);
    unsigned int r = u + 0x7fffu + ((u >> 16) & 1u);  // RNE
    return (unsigned short)(r >> 16);
}
__device__ __forceinline__ unsigned int pk2(float a, float b) {
    return (unsigned int)__builtin_amdgcn_cvt_pk_fp8_f32(a, b, 0, false);  // OCP e4m3 x2
}
__device__ __forceinline__ unsigned char f2q(float a) { return (unsigned char)(pk2(a, a) & 0xff); }
__device__ __forceinline__ void unp4(unsigned int u, float* f) {
    auto lo = __builtin_amdgcn_cvt_pk_f32_fp8((int)u, false);
    auto hi = __builtin_amdgcn_cvt_pk_f32_fp8((int)u, true);
    f[0] = lo[0]; f[1] = lo[1]; f[2] = hi[0]; f[3] = hi[1];
}
// sigmoid via raw v_rcp_f32 (1 instr). The default `1.f/x` compiles to the
// ~10-instr IEEE division sequence (no fast-math at HIP level); with fp8
// quantization everywhere, 1-ulp rcp is far below the noise floor.
__device__ __forceinline__ float sigf(float x) {
    return __builtin_amdgcn_rcpf(1.f + __expf(-x));
}
// tanh(y) = 2*sigmoid(2y) - 1
__device__ __forceinline__ float tanhfast2y(float twoy) { return 2.f * sigf(twoy) - 1.f; }

// ---------------------------------------------------------------------------
// Weight prep (identical math). Zeroes 32 pipeline flags and d_out.
// ---------------------------------------------------------------------------
__global__ void prep_weights(const float* __restrict__ Wz, const float* __restrict__ Wr,
                             const float* __restrict__ Wh, const float* __restrict__ Uz,
                             const float* __restrict__ Ur, const float* __restrict__ Uh,
                             unsigned char* __restrict__ ws, float* __restrict__ out) {
    int T = blockIdx.x * 256 + threadIdx.x;  // 1536*256 = 393216
    if (T == 0) out[0] = 0.f;
    if (T < 32) ((int*)(ws + OFF_FLG))[T] = 0;   // pipeline flags (ws re-poisoned each call)
    if (T < 196608) {  // U-mats, fp8
        int e = T & 3, half = (T >> 2) & 1, lane = (T >> 3) & 63;
        int kp = (T >> 9) & 3, nt = (T >> 11) & 15, mu = T >> 15;
        int g = mu % 3, l = mu / 3;
        const float* s = (g == 0 ? Uz : g == 1 ? Ur : Uh) + l * 65536;
        int n  = nt * 16 + (lane & 15);
        int k0 = (2 * kp + half) * 32 + (lane >> 4) * 8 + 2 * e;
        float w0 = s[(k0 << 8) + n] * 8.f;        // x8: dodge e4m3 denormals
        float w1 = s[((k0 + 1) << 8) + n] * 8.f;  // undone by 0.125 post-acc
        int addr = ((mu * 16 + nt) * 4 + kp) * 1024 + lane * 16 + half * 8 + 2 * e;
        *(unsigned short*)(ws + addr) = (unsigned short)(pk2(w0, w1) & 0xffff);
    } else {           // W-mats, bf16
        int T2 = T - 196608;
        int e = T2 & 3, lane = (T2 >> 2) & 63;
        int kf = (T2 >> 8) & 7, nt = (T2 >> 11) & 15, mw = T2 >> 15;
        int g = mw % 3, l = mw / 3;
        const float* s = (g == 0 ? Wz : g == 1 ? Wr : Wh) + l * 65536;
        int n  = nt * 16 + (lane & 15);
        int k0 = kf * 32 + (lane >> 4) * 8 + 2 * e;
        unsigned int v = (unsigned int)f2bf(s[(k0 << 8) + n]) |
                         ((unsigned int)f2bf(s[((k0 + 1) << 8) + n]) << 16);
        int addr = ((mw * 16 + nt) * 8 + kf) * 1024 + lane * 16 + 4 * e;
        *(unsigned int*)(ws + OFF_WPW + addr) = v;
    }
}

// ---------------------------------------------------------------------------
// Stage-A projection GEMM (standalone): XP = x @ W(l0). Grid 2048.
// ---------------------------------------------------------------------------
template <int F32SRC>
__global__ __launch_bounds__(1024) void proj_kernel(const void* __restrict__ src,
                                                    const unsigned char* __restrict__ wpW,
                                                    unsigned int* __restrict__ xpo, int matbase) {
    const int bgt = blockIdx.x;
    const int t = bgt & 511, bg = bgt >> 9;
    const int tid = threadIdx.x, wave = tid >> 6, lane = tid & 63;
    const int l15 = lane & 15, quad = lane >> 4;
    const size_t rowoff = ((size_t)(bg * 16 + l15) * 512 + t) * 256;

    bf16x8 af[8];
    if (F32SRC) {
        const float* s = (const float*)src + rowoff;
#pragma unroll
        for (int kf = 0; kf < 8; ++kf) {
            float4 a = *(const float4*)(s + kf * 32 + quad * 8);
            float4 b = *(const float4*)(s + kf * 32 + quad * 8 + 4);
            union { unsigned short u[8]; bf16x8 v; } cv;
            cv.u[0] = f2bf(a.x); cv.u[1] = f2bf(a.y); cv.u[2] = f2bf(a.z); cv.u[3] = f2bf(a.w);
            cv.u[4] = f2bf(b.x); cv.u[5] = f2bf(b.y); cv.u[6] = f2bf(b.z); cv.u[7] = f2bf(b.w);
            af[kf] = cv.v;
        }
    } else {
        const unsigned short* s = (const unsigned short*)src + rowoff;
#pragma unroll
        for (int kf = 0; kf < 8; ++kf) af[kf] = *(const bf16x8*)(s + kf * 32 + quad * 8);
    }

    floatx4 az = {0.f, 0.f, 0.f, 0.f}, ar = az, ah = az;
    const unsigned char* bz = wpW + (size_t)(((matbase + 0) * 16 + wave) * 8) * 1024 + lane * 16;
    const unsigned char* br = wpW + (size_t)(((matbase + 1) * 16 + wave) * 8) * 1024 + lane * 16;
    const unsigned char* bh = wpW + (size_t)(((matbase + 2) * 16 + wave) * 8) * 1024 + lane * 16;
#pragma unroll
    for (int kf = 0; kf < 8; ++kf) {
        az = MFMA_BF16(af[kf], *(const bf16x8*)(bz + kf * 1024), az, 0, 0, 0);
        ar = MFMA_BF16(af[kf], *(const bf16x8*)(br + kf * 1024), ar, 0, 0, 0);
        ah = MFMA_BF16(af[kf], *(const bf16x8*)(bh + kf * 1024), ah, 0, 0, 0);
    }
    const size_t ob = (size_t)bgt * 3072 + wave * 64 + lane;
    xpo[ob]        = pk2(16.f * az[0], 16.f * az[1]) | (pk2(16.f * az[2], 16.f * az[3]) << 16);
    xpo[ob + 1024] = pk2(16.f * ar[0], 16.f * ar[1]) | (pk2(16.f * ar[2], 16.f * ar[3]) << 16);
    xpo[ob + 2048] = pk2(16.f * ah[0], 16.f * ah[1]) | (pk2(16.f * ah[2], 16.f * ah[3]) << 16);
}

// ---------------------------------------------------------------------------
// GRU scan body (R2 math). WAIT==1: wait on MIN of 4 upstream flags.
// POST==1: publish pflag per CHUNK. Per-step barriers are LDS-only
// (BAR_LDS). Full __syncthreads only at WAIT/POST chunk boundaries.
// ---------------------------------------------------------------------------
template <int SCORE, int WAIT, int POST>
__device__ __forceinline__ void scan_body(
    const unsigned int* __restrict__ xp, const unsigned char* __restrict__ wpU,
    int lbase, int bg, unsigned short* __restrict__ hnout,
    const int* __restrict__ xlen, const float* __restrict__ xlab,
    const float* __restrict__ Wo, float* __restrict__ out,
    int* wflags, int* pflag,
    unsigned char (*s1q)[AST], unsigned char (*rsq)[AST], float (*s1o)[264],
    float* wo1s, int* s_rdy, int tmax)
{
    const int tid = threadIdx.x, wave = tid >> 6, lane = tid & 63;
    const int l15 = lane & 15, quad = lane >> 4;
    const int b0 = bg * 16;

    for (int i = tid; i < 16 * AST; i += 1024) ((unsigned char*)s1q)[i] = 0;
    if (SCORE && tid < DIM) wo1s[tid] = Wo[2 * tid + 1];
    const int lenr = xlen[b0 + l15];
    const float labr = SCORE ? xlab[b0 + l15] : 0.f;
    (void)lenr; (void)labr;

    const int nt = wave;
    const int colA = nt * 16 + l15, rowb = quad * 4;

    // register-resident U fragments for this wave's 16-col tile
    long uz[8], ur[8], uh[8];
    {
        const unsigned char* pz = wpU + (size_t)(((lbase + 0) * 16 + nt) * 4) * 1024 + lane * 16;
        const unsigned char* pr = wpU + (size_t)(((lbase + 1) * 16 + nt) * 4) * 1024 + lane * 16;
        const unsigned char* ph = wpU + (size_t)(((lbase + 2) * 16 + nt) * 4) * 1024 + lane * 16;
#pragma unroll
        for (int kf = 0; kf < 8; ++kf) {
            int o = (kf >> 1) * 1024 + (kf & 1) * 8;
            uz[kf] = *(const long*)(pz + o);
            ur[kf] = *(const long*)(pr + o);
            uh[kf] = *(const long*)(ph + o);
        }
    }
    float s1r[4] = {};
    float accl = 0.f;
    int ready = 0;
    __syncthreads();

    for (int t = 0; t < tmax; ++t) {
        if (WAIT && t >= ready) {
            if (tid == 0) {
                int vv, g = 0;
                for (;;) {
                    int m0 = __hip_atomic_load(wflags + 0, __ATOMIC_RELAXED, __HIP_MEMORY_SCOPE_AGENT);
                    int m1 = __hip_atomic_load(wflags + 1, __ATOMIC_RELAXED, __HIP_MEMORY_SCOPE_AGENT);
                    int m2 = __hip_atomic_load(wflags + 2, __ATOMIC_RELAXED, __HIP_MEMORY_SCOPE_AGENT);
                    int m3 = __hip_atomic_load(wflags + 3, __ATOMIC_RELAXED, __HIP_MEMORY_SCOPE_AGENT);
                    int a = m0 < m1 ? m0 : m1, b = m2 < m3 ? m2 : m3;
                    vv = a < b ? a : b;
                    if (vv > t || ++g > (1 << 19)) break;   // fail visibly, never hang
                    __builtin_amdgcn_s_sleep(2);
                }
                __threadfence();          // agent acquire before data reads
                *s_rdy = vv > t ? vv : t + 1;
            }
            __syncthreads();
            ready = *s_rdy;
        }

        const unsigned int* xpt = xp + (size_t)(bg * 512 + t) * 3072 + lane;
        unsigned int xz = xpt[nt * 64];
        unsigned int xr = xpt[1024 + nt * 64];
        unsigned int xh = xpt[2048 + nt * 64];

        // ---- phase 1: r (on the critical path) + z-MFMAs (acc dangles) ----
        long sf[8];
#pragma unroll
        for (int kf = 0; kf < 8; ++kf) sf[kf] = *(const long*)&s1q[l15][kf * 32 + quad * 8];
        floatx4 za = {0.f, 0.f, 0.f, 0.f}, ra = za;
#pragma unroll
        for (int kf = 0; kf < 8; ++kf) {
            ra = MFMA_FP8(sf[kf], ur[kf], ra, 0, 0, 0);
            za = MFMA_FP8(sf[kf], uz[kf], za, 0, 0, 0);
        }
        float xrf[4];
        unp4(xr, xrf);
#pragma unroll
        for (int i = 0; i < 4; ++i) {
            float r = sigf(0.125f * ra[i] + 0.0625f * xrf[i]);
            rsq[rowb + i][colA] = f2q(r * s1r[i]);
        }
        BAR_LDS();   // LDS-only: XP loads / HN stores stay in flight

        // ---- phase 2: h; z-sigmoid overlaps the Uh MFMA ----
        long rf[8];
#pragma unroll
        for (int kf = 0; kf < 8; ++kf) rf[kf] = *(const long*)&rsq[l15][kf * 32 + quad * 8];
        floatx4 ha = {0.f, 0.f, 0.f, 0.f};
#pragma unroll
        for (int kf = 0; kf < 8; ++kf) ha = MFMA_FP8(rf[kf], uh[kf], ha, 0, 0, 0);
        float xzf[4], xhf[4];
        unp4(xz, xzf); unp4(xh, xhf);
#pragma unroll
        for (int i = 0; i < 4; ++i) {
            float z = sigf(0.125f * za[i] + 0.0625f * xzf[i]);
            float h = tanhfast2y(0.25f * ha[i] + 0.125f * xhf[i]);  // tanh(0.125ha+0.0625xh)
            float hn = (1.f - z) * s1r[i] + z * h;
            s1r[i] = hn;
            s1q[rowb + i][colA] = f2q(hn);
            s1o[rowb + i][colA] = hn;
        }
        BAR_LDS();   // LDS-only

        if (!SCORE) {
            // cooperative hn0 write: row=tid>>6, 4 cols/thread; coalesced 8B stores
            const int r = tid >> 6, c = (tid & 63) * 4;
            float4 f0 = *(const float4*)&s1o[r][c];
            uint2 o2;
            o2.x = f2bf(f0.x) | ((unsigned)f2bf(f0.y) << 16);
            o2.y = f2bf(f0.z) | ((unsigned)f2bf(f0.w) << 16);
            *(uint2*)(hnout + ((size_t)(b0 + r) * 512 + t) * 256 + c) = o2;
        } else if (wave == 0) {
            const int row = l15, c0 = quad * 64;
            float p = 0.f;
#pragma unroll
            for (int u = 0; u < 64; u += 4) {
                float4 sv = *(const float4*)&s1o[row][c0 + u];
                float4 wv = *(const float4*)&wo1s[c0 + u];
                p = fmaf(sv.x, wv.x, p); p = fmaf(sv.y, wv.y, p);
                p = fmaf(sv.z, wv.z, p); p = fmaf(sv.w, wv.w, p);
            }
            p += __shfl_xor(p, 16);
            p += __shfl_xor(p, 32);
            if (lane < 16 && t < lenr) {
                float sc = sigf(p);
                float d = labr - sc;
                accl = fmaf(d, d, accl);
            }
        }

        if (POST && (((t & (CHUNK - 1)) == (CHUNK - 1)) || t == tmax - 1)) {
            __syncthreads();   // FULL drain: all waves' HN stores (vmcnt0) before fence
            if (tid == 0) {
                __threadfence();   // agent release: push chunk data to coherent point
                __hip_atomic_store(pflag, t + 1, __ATOMIC_RELEASE, __HIP_MEMORY_SCOPE_AGENT);
            }
        }
    }

    if (SCORE && wave == 0) {
        accl += __shfl_xor(accl, 1);
        accl += __shfl_xor(accl, 2);
        accl += __shfl_xor(accl, 4);
        accl += __shfl_xor(accl, 8);
        if (lane == 0) atomicAdd(out, accl);
    }
}

// ---------------------------------------------------------------------------
// Fused 3-stage pipeline, 24 WGs (R2 topology):
//   blocks 0-3  : layer-0 scan (posts flags[bg] per chunk)
//   blocks 4-19 : projB, 4 WGs per bg; WG p owns t in [base+4p, base+4p+4) of
//                 each chunk; waits flags[bg], posts flags[4+bg*4+p]
//   blocks 20-23: layer-1 scan + loss (waits MIN of the bg's 4 projB flags)
// ---------------------------------------------------------------------------
__global__ __launch_bounds__(1024, 4) void fused_pipeline(
    const unsigned int* __restrict__ XP, unsigned int* __restrict__ HP,
    const unsigned char* __restrict__ wpU, const unsigned char* __restrict__ wpW,
    unsigned short* __restrict__ HN,
    const int* __restrict__ xlen, const float* __restrict__ xlab,
    const float* __restrict__ Wo, float* __restrict__ out, int* flags)
{
    __shared__ __align__(16) unsigned char s1q[16][AST];
    __shared__ __align__(16) unsigned char rsq[16][AST];
    __shared__ __align__(16) float s1o[16][264];
    __shared__ float wo1s[DIM];
    __shared__ int s_rdy;

    const int bid = blockIdx.x;
    int role, bg, p = 0;
    if (bid < 4)       { role = 0; bg = bid; }
    else if (bid < 20) { role = 1; bg = (bid - 4) >> 2; p = (bid - 4) & 3; }
    else               { role = 2; bg = bid - 20; }

    const int tid = threadIdx.x, wave = tid >> 6, lane = tid & 63;
    const int l15 = lane & 15, quad = lane >> 4;
    const int b0 = bg * 16;

    // uniform tmax = max xlen over this bg's 16 rows (same in all stages)
    int v = xlen[b0 + l15];
#pragma unroll
    for (int o = 1; o < 16; o <<= 1) v = max(v, __shfl_xor(v, o));
    const int tmax = __builtin_amdgcn_readfirstlane(v);

    if (role == 0) {
        scan_body<0, 0, 1>(XP, wpU, 0, bg, HN, xlen, xlab, Wo, out,
                           nullptr, flags + bg, s1q, rsq, s1o, wo1s, &s_rdy, tmax);
    } else if (role == 2) {
        scan_body<1, 1, 0>(HP, wpU, 3, bg, nullptr, xlen, xlab, Wo, out,
                           flags + 4 + bg * 4, nullptr, s1q, rsq, s1o, wo1s, &s_rdy, tmax);
    } else {
        // ---- projB stage: HP[t] = HN[t] @ W(l1); this WG owns 4 t per chunk ----
        int* wf = flags + bg;
        int* pf = flags + 4 + bg * 4 + p;
        const unsigned char* bz = wpW + (size_t)(((3 + 0) * 16 + wave) * 8) * 1024 + lane * 16;
        const unsigned char* br = wpW + (size_t)(((3 + 1) * 16 + wave) * 8) * 1024 + lane * 16;
        const unsigned char* bh = wpW + (size_t)(((3 + 2) * 16 + wave) * 8) * 1024 + lane * 16;
        for (int base = 0; base < tmax; base += CHUNK) {
            const int target = (base + CHUNK < tmax) ? base + CHUNK : tmax;
            if (tid == 0) {
                int vv, g = 0;
                for (;;) {
                    vv = __hip_atomic_load(wf, __ATOMIC_RELAXED, __HIP_MEMORY_SCOPE_AGENT);
                    if (vv >= target || ++g > (1 << 19)) break;
                    __builtin_amdgcn_s_sleep(2);
                }
                __threadfence();   // acquire: see scan0's HN chunk
            }
            __syncthreads();       // no wave reads HN before the inv

            const int t0 = base + p * 4;
            const int t1 = (t0 + 4 < tmax) ? t0 + 4 : tmax;
            for (int t = t0; t < t1; ++t) {
                const unsigned short* sA = HN + ((size_t)(b0 + l15) * 512 + t) * 256;
                bf16x8 af[8];
#pragma unroll
                for (int kf = 0; kf < 8; ++kf) af[kf] = *(const bf16x8*)(sA + kf * 32 + quad * 8);
                floatx4 az = {0.f, 0.f, 0.f, 0.f}, ar = az, ah = az;
#pragma unroll
                for (int kf = 0; kf < 8; ++kf) {
                    az = MFMA_BF16(af[kf], *(const bf16x8*)(bz + kf * 1024), az, 0, 0, 0);
                    ar = MFMA_BF16(af[kf], *(const bf16x8*)(br + kf * 1024), ar, 0, 0, 0);
                    ah = MFMA_BF16(af[kf], *(const bf16x8*)(bh + kf * 1024), ah, 0, 0, 0);
                }
                const size_t ob = (size_t)(bg * 512 + t) * 3072 + wave * 64 + lane;
                HP[ob]        = pk2(16.f * az[0], 16.f * az[1]) | (pk2(16.f * az[2], 16.f * az[3]) << 16);
                HP[ob + 1024] = pk2(16.f * ar[0], 16.f * ar[1]) | (pk2(16.f * ar[2], 16.f * ar[3]) << 16);
                HP[ob + 2048] = pk2(16.f * ah[0], 16.f * ah[1]) | (pk2(16.f * ah[2], 16.f * ah[3]) << 16);
            }

            __syncthreads();   // all waves' HP stores drained (vmcnt0 before barrier)
            if (tid == 0) {
                __threadfence();   // release: push HP chunk to coherent point
                __hip_atomic_store(pf, base + CHUNK, __ATOMIC_RELEASE, __HIP_MEMORY_SCOPE_AGENT);
            }
        }
    }
}

extern "C" void kernel_launch(void* const* d_in, const int* in_sizes, int n_in,
                              void* d_out, int out_size, void* d_ws, size_t ws_size,
                              hipStream_t stream) {
    const float* x    = (const float*)d_in[0];
    const int*   xlen = (const int*)d_in[1];
    const float* xlab = (const float*)d_in[2];
    const float* Wz   = (const float*)d_in[3];
    const float* Uz   = (const float*)d_in[4];
    const float* Wr   = (const float*)d_in[5];
    const float* Ur   = (const float*)d_in[6];
    const float* Wh   = (const float*)d_in[7];
    const float* Uh   = (const float*)d_in[8];
    const float* Wo   = (const float*)d_in[9];
    float* out = (float*)d_out;

    unsigned char* ws  = (unsigned char*)d_ws;
    unsigned char* wpU = ws;                                 // fp8 U-frags, 384 KB
    unsigned char* wpW = ws + OFF_WPW;                       // bf16 W-frags, 768 KB
    int*           FLG = (int*)(ws + OFF_FLG);               // pipeline flags
    unsigned int*  XP  = (unsigned int*)(ws + OFF_XP);       // 25.2 MB
    unsigned int*  HP  = (unsigned int*)(ws + OFF_HP);       // 25.2 MB
    unsigned short* HN = (unsigned short*)(ws + OFF_HN);     // 16.8 MB

    // ws re-poisoned every call -> rebuild everything (incl. flags) each time.
    prep_weights<<<1536, 256, 0, stream>>>(Wz, Wr, Wh, Uz, Ur, Uh, ws, out);
    proj_kernel<1><<<2048, 1024, 0, stream>>>(x, wpW, XP, 0);   // A: x @ W(l0)
    fused_pipeline<<<24, 1024, 0, stream>>>(XP, HP, wpU, wpW, HN,
                                            xlen, xlab, Wo, out, FLG);
}